// Round 5
// baseline (266.609 us; speedup 1.0000x reference)
//
#include <hip/hip_runtime.h>

#define BDIM 8
#define NPTS 4096
#define KNEI 20
#define BN (BDIM*NPTS)        // 32768
#define NKCNT (NPTS*KNEI)     // 81920
#define EPSI 1e-5f
#define SLOPE 0.01f

typedef __attribute__((ext_vector_type(8))) short bf16x8;
typedef __attribute__((ext_vector_type(4))) float f32x4;
typedef __attribute__((ext_vector_type(4))) unsigned int u32x4;

__device__ __forceinline__ unsigned short f2bf(float f) {
    unsigned u = __builtin_bit_cast(unsigned, f);
    u += 0x7FFFu + ((u >> 16) & 1u);
    return (unsigned short)(u >> 16);
}
__device__ __forceinline__ float bf2f(unsigned short h) {
    unsigned u = ((unsigned)h) << 16;
    return __builtin_bit_cast(float, u);
}

// ---------------- K0: u = x*W1a^T, v = x*(W1b-W1a)^T  (bf16 out) ----------------
__global__ __launch_bounds__(256) void k0_uv(const float* __restrict__ x,
        const float* __restrict__ W1, unsigned short* __restrict__ u,
        unsigned short* __restrict__ v) {
    __shared__ float wlds[64 * 129];
    __shared__ float xs[16 * 64];
    int tid = threadIdx.x;
    int m0 = blockIdx.x * 16;
    for (int i = tid; i < 8192; i += 256)
        wlds[(i >> 7) * 129 + (i & 127)] = W1[i];
    for (int i = tid; i < 1024; i += 256)
        xs[i] = x[m0 * 64 + i];
    __syncthreads();
    int o = tid & 63;
    int r0 = tid >> 6;
    float au[4] = {0.f, 0.f, 0.f, 0.f};
    float av[4] = {0.f, 0.f, 0.f, 0.f};
    for (int c = 0; c < 64; ++c) {
        float wa = wlds[o * 129 + c];
        float wb = wlds[o * 129 + 64 + c];
        float wd = wb - wa;
#pragma unroll
        for (int jj = 0; jj < 4; ++jj) {
            float xv = xs[(r0 + jj * 4) * 64 + c];
            au[jj] += xv * wa;
            av[jj] += xv * wd;
        }
    }
#pragma unroll
    for (int jj = 0; jj < 4; ++jj) {
        int m = m0 + r0 + jj * 4;
        u[m * 64 + o] = f2bf(au[jj]);
        v[m * 64 + o] = f2bf(av[jj]);
    }
}

// ---- helper: load A-fragments (W row-major [64][64] fp32 -> bf16 frags) ----
__device__ __forceinline__ void load_bfrags(const float* __restrict__ W,
        int l15, int q, bf16x8 bw[4][2]) {
#pragma unroll
    for (int mt = 0; mt < 4; ++mt)
#pragma unroll
        for (int kc = 0; kc < 2; ++kc) {
            const float* wp = W + (mt * 16 + l15) * 64 + kc * 32 + q * 8;
            bf16x8 t;
#pragma unroll
            for (int j = 0; j < 8; ++j) t[j] = (short)f2bf(wp[j]);
            bw[mt][kc] = t;
        }
}

// ---------------- K1: stats1 of h1 = u[ind]+v — pure register gather ----------------
// 512 blocks x 256 thr; thread = (point, channel-quarter). No LDS tile, no DMA.
__global__ __launch_bounds__(256) void k1_stats1(const unsigned short* __restrict__ u,
        const unsigned short* __restrict__ v, const int* __restrict__ ind,
        float* __restrict__ s1) {
    __shared__ float red[512];
    int tid = threadIdx.x;
    int lane = tid & 63, w = tid >> 6;
    int pt = blockIdx.x * 64 + (tid >> 2);
    int qt = tid & 3;
    int b = pt >> 12;                        // 4096 points per batch
    const unsigned short* vp = v + (size_t)pt * 64 + qt * 16;
    u32x4 v0 = *(const u32x4*)vp;
    u32x4 v1 = *(const u32x4*)(vp + 8);
    float vf[16];
#pragma unroll
    for (int d = 0; d < 4; ++d) {
        vf[2 * d]     = bf2f((unsigned short)(v0[d] & 0xFFFF));
        vf[2 * d + 1] = bf2f((unsigned short)(v0[d] >> 16));
        vf[8 + 2 * d]     = bf2f((unsigned short)(v1[d] & 0xFFFF));
        vf[8 + 2 * d + 1] = bf2f((unsigned short)(v1[d] >> 16));
    }
    int idxs[20];
    const int* ip = ind + pt * 20;
#pragma unroll
    for (int k = 0; k < 20; ++k) idxs[k] = ip[k];
    float ss[16], qs[16];
#pragma unroll
    for (int j = 0; j < 16; ++j) { ss[j] = 0.f; qs[j] = 0.f; }
#pragma unroll 4
    for (int k = 0; k < 20; ++k) {
        const unsigned short* up = u + (size_t)idxs[k] * 64 + qt * 16;
        u32x4 u0 = *(const u32x4*)up;
        u32x4 u1 = *(const u32x4*)(up + 8);
#pragma unroll
        for (int d = 0; d < 4; ++d) {
            float h0 = bf2f((unsigned short)(u0[d] & 0xFFFF)) + vf[2 * d];
            float h1 = bf2f((unsigned short)(u0[d] >> 16)) + vf[2 * d + 1];
            float h2 = bf2f((unsigned short)(u1[d] & 0xFFFF)) + vf[8 + 2 * d];
            float h3 = bf2f((unsigned short)(u1[d] >> 16)) + vf[8 + 2 * d + 1];
            ss[2 * d] += h0;         qs[2 * d] = fmaf(h0, h0, qs[2 * d]);
            ss[2 * d + 1] += h1;     qs[2 * d + 1] = fmaf(h1, h1, qs[2 * d + 1]);
            ss[8 + 2 * d] += h2;     qs[8 + 2 * d] = fmaf(h2, h2, qs[8 + 2 * d]);
            ss[8 + 2 * d + 1] += h3; qs[8 + 2 * d + 1] = fmaf(h3, h3, qs[8 + 2 * d + 1]);
        }
    }
    // reduce across lane>>2 groups (shfl tree), quarters live in lane&3
#pragma unroll
    for (int m = 4; m <= 32; m <<= 1)
#pragma unroll
        for (int j = 0; j < 16; ++j) {
            ss[j] += __shfl_xor(ss[j], m, 64);
            qs[j] += __shfl_xor(qs[j], m, 64);
        }
    if (lane < 4) {
#pragma unroll
        for (int j = 0; j < 16; ++j) {
            int c = lane * 16 + j;
            red[w * 128 + c] = ss[j];
            red[w * 128 + 64 + c] = qs[j];
        }
    }
    __syncthreads();
    if (tid < 128) {
        int st = tid >> 6, c = tid & 63;
        float a = red[st * 64 + c] + red[128 + st * 64 + c]
                + red[256 + st * 64 + c] + red[384 + st * 64 + c];
        atomicAdd(&s1[st * 512 + b * 64 + c], a);
    }
}

// ------ K2': direct-gather frags -> norm1+lrelu -> GEMM2 -> shfl stats2 (no tile) ------
__global__ __launch_bounds__(256, 3) void k2_stats2(const unsigned short* __restrict__ u,
        const unsigned short* __restrict__ v, const int* __restrict__ ind,
        const float* __restrict__ W2, const float* __restrict__ s1,
        float* __restrict__ s2) {
    __shared__ int inds[320];
    __shared__ float red[512];
    int tid = threadIdx.x;
    int lane = tid & 63, w = tid >> 6;
    int l15 = lane & 15, q = lane >> 4;
    int b = blockIdx.x >> 8;
    int n0 = (blockIdx.x & 255) << 4;
    int base = b * NPTS + n0;
    int base20 = base * 20;
    bf16x8 aw[4][2];
    load_bfrags(W2, l15, q, aw);
    const float inv = 1.0f / (float)NKCNT;
    float r1[2][8], mr1[2][8];
#pragma unroll
    for (int kc = 0; kc < 2; ++kc)
#pragma unroll
        for (int j = 0; j < 8; ++j) {
            int c = kc * 32 + q * 8 + j;
            float mm = s1[b * 64 + c] * inv;
            float vv = s1[512 + b * 64 + c] * inv - mm * mm;
            float rs = rsqrtf(vv + EPSI);
            r1[kc][j] = rs; mr1[kc][j] = -mm * rs;
        }
    for (int i = tid; i < 320; i += 256) inds[i] = ind[base20 + i];
    __syncthreads();
    // issue all u gathers (raw into bf), remember point rows
    bf16x8 bf[5][2];
    int prow[5];
#pragma unroll
    for (int nt = 0; nt < 5; ++nt) {
        int row = (w * 5 + nt) * 16 + l15;
        int idx = inds[row];
        prow[nt] = (row * 3277) >> 16;       // row/20
        const unsigned short* up = u + (size_t)idx * 64 + q * 8;
        bf[nt][0] = *(const bf16x8*)up;
        bf[nt][1] = *(const bf16x8*)(up + 32);
    }
    // v + convert: a1 = lrelu(norm1(u+v))
#pragma unroll
    for (int nt = 0; nt < 5; ++nt) {
        const unsigned short* vp = v + (size_t)(base + prow[nt]) * 64 + q * 8;
#pragma unroll
        for (int kc = 0; kc < 2; ++kc) {
            u32x4 vr = *(const u32x4*)(vp + kc * 32);
            u32x4 ur = __builtin_bit_cast(u32x4, bf[nt][kc]);
            bf16x8 o;
#pragma unroll
            for (int d = 0; d < 4; ++d) {
                float h0 = bf2f((unsigned short)(ur[d] & 0xFFFF)) + bf2f((unsigned short)(vr[d] & 0xFFFF));
                float h1 = bf2f((unsigned short)(ur[d] >> 16)) + bf2f((unsigned short)(vr[d] >> 16));
                float t0 = fmaf(h0, r1[kc][2 * d], mr1[kc][2 * d]);
                float t1 = fmaf(h1, r1[kc][2 * d + 1], mr1[kc][2 * d + 1]);
                t0 = fmaxf(t0, SLOPE * t0);
                t1 = fmaxf(t1, SLOPE * t1);
                o[2 * d] = (short)f2bf(t0);
                o[2 * d + 1] = (short)f2bf(t1);
            }
            bf[nt][kc] = o;
        }
    }
    // GEMM2 with per-mt register stats + shfl reduce over l15
#pragma unroll
    for (int mt = 0; mt < 4; ++mt) {
        float s4[4] = {0.f, 0.f, 0.f, 0.f}, q4[4] = {0.f, 0.f, 0.f, 0.f};
#pragma unroll
        for (int nt = 0; nt < 5; ++nt) {
            f32x4 acc = (f32x4){0.f, 0.f, 0.f, 0.f};
            acc = __builtin_amdgcn_mfma_f32_16x16x32_bf16(aw[mt][0], bf[nt][0], acc, 0, 0, 0);
            acc = __builtin_amdgcn_mfma_f32_16x16x32_bf16(aw[mt][1], bf[nt][1], acc, 0, 0, 0);
#pragma unroll
            for (int i = 0; i < 4; ++i) {
                s4[i] += acc[i];
                q4[i] = fmaf(acc[i], acc[i], q4[i]);
            }
        }
#pragma unroll
        for (int m = 1; m <= 8; m <<= 1)
#pragma unroll
            for (int i = 0; i < 4; ++i) {
                s4[i] += __shfl_xor(s4[i], m, 64);
                q4[i] += __shfl_xor(q4[i], m, 64);
            }
        if (l15 == 0) {
#pragma unroll
            for (int i = 0; i < 4; ++i) {
                int c = mt * 16 + q * 4 + i;
                red[w * 128 + c] = s4[i];
                red[w * 128 + 64 + c] = q4[i];
            }
        }
    }
    __syncthreads();
    if (tid < 128) {
        int st = tid >> 6, c = tid & 63;
        float a = red[st * 64 + c] + red[128 + st * 64 + c]
                + red[256 + st * 64 + c] + red[384 + st * 64 + c];
        atomicAdd(&s2[st * 512 + b * 64 + c], a);
    }
}

// -- K3': direct-gather -> GEMM2 -> norm2 (write-side) -> a2 tile -> GEMM3 -> max/stats --
__global__ __launch_bounds__(256, 3) void k3_gemm3(const unsigned short* __restrict__ u,
        const unsigned short* __restrict__ v, const int* __restrict__ ind,
        const float* __restrict__ W2, const float* __restrict__ W3,
        const float* __restrict__ s1, const float* __restrict__ s2,
        float* __restrict__ s3, float* __restrict__ out) {
    __shared__ __align__(16) unsigned char tile[40960];
    __shared__ int inds[320];
    __shared__ float red[1024];
    int tid = threadIdx.x;
    int lane = tid & 63, w = tid >> 6;
    int l15 = lane & 15, q = lane >> 4;
    int b = blockIdx.x >> 8;
    int n0 = (blockIdx.x & 255) << 4;
    int base = b * NPTS + n0;
    int base20 = base * 20;
    bf16x8 aw[4][2];
    load_bfrags(W2, l15, q, aw);
    const float inv = 1.0f / (float)NKCNT;
    float r1[2][8], mr1[2][8];
#pragma unroll
    for (int kc = 0; kc < 2; ++kc)
#pragma unroll
        for (int j = 0; j < 8; ++j) {
            int c = kc * 32 + q * 8 + j;
            float mm = s1[b * 64 + c] * inv;
            float vv = s1[512 + b * 64 + c] * inv - mm * mm;
            float rs = rsqrtf(vv + EPSI);
            r1[kc][j] = rs; mr1[kc][j] = -mm * rs;
        }
    float r2c[16], mr2c[16];
#pragma unroll
    for (int e = 0; e < 16; ++e) {
        int c = (e >> 2) * 16 + q * 4 + (e & 3);
        float mm = s2[b * 64 + c] * inv;
        float vv = s2[512 + b * 64 + c] * inv - mm * mm;
        float rs = rsqrtf(vv + EPSI);
        r2c[e] = rs; mr2c[e] = -mm * rs;
    }
    for (int i = tid; i < 320; i += 256) inds[i] = ind[base20 + i];
    __syncthreads();
    // direct gather + convert -> a1 frags
    bf16x8 bf[5][2];
    int prow[5];
#pragma unroll
    for (int nt = 0; nt < 5; ++nt) {
        int row = (w * 5 + nt) * 16 + l15;
        int idx = inds[row];
        prow[nt] = (row * 3277) >> 16;
        const unsigned short* up = u + (size_t)idx * 64 + q * 8;
        bf[nt][0] = *(const bf16x8*)up;
        bf[nt][1] = *(const bf16x8*)(up + 32);
    }
#pragma unroll
    for (int nt = 0; nt < 5; ++nt) {
        const unsigned short* vp = v + (size_t)(base + prow[nt]) * 64 + q * 8;
#pragma unroll
        for (int kc = 0; kc < 2; ++kc) {
            u32x4 vr = *(const u32x4*)(vp + kc * 32);
            u32x4 ur = __builtin_bit_cast(u32x4, bf[nt][kc]);
            bf16x8 o;
#pragma unroll
            for (int d = 0; d < 4; ++d) {
                float h0 = bf2f((unsigned short)(ur[d] & 0xFFFF)) + bf2f((unsigned short)(vr[d] & 0xFFFF));
                float h1 = bf2f((unsigned short)(ur[d] >> 16)) + bf2f((unsigned short)(vr[d] >> 16));
                float t0 = fmaf(h0, r1[kc][2 * d], mr1[kc][2 * d]);
                float t1 = fmaf(h1, r1[kc][2 * d + 1], mr1[kc][2 * d + 1]);
                t0 = fmaxf(t0, SLOPE * t0);
                t1 = fmaxf(t1, SLOPE * t1);
                o[2 * d] = (short)f2bf(t0);
                o[2 * d + 1] = (short)f2bf(t1);
            }
            bf[nt][kc] = o;
        }
    }
    // GEMM2 + write-side norm2+lrelu -> a2 tile (swizzled)
#pragma unroll
    for (int nt = 0; nt < 5; ++nt) {
        int row = (w * 5 + nt) * 16 + l15;
        int r7 = row & 7;
#pragma unroll
        for (int mt = 0; mt < 4; ++mt) {
            f32x4 acc = (f32x4){0.f, 0.f, 0.f, 0.f};
            acc = __builtin_amdgcn_mfma_f32_16x16x32_bf16(aw[mt][0], bf[nt][0], acc, 0, 0, 0);
            acc = __builtin_amdgcn_mfma_f32_16x16x32_bf16(aw[mt][1], bf[nt][1], acc, 0, 0, 0);
            float t0 = fmaf(acc[0], r2c[mt * 4 + 0], mr2c[mt * 4 + 0]); t0 = fmaxf(t0, SLOPE * t0);
            float t1 = fmaf(acc[1], r2c[mt * 4 + 1], mr2c[mt * 4 + 1]); t1 = fmaxf(t1, SLOPE * t1);
            float t2 = fmaf(acc[2], r2c[mt * 4 + 2], mr2c[mt * 4 + 2]); t2 = fmaxf(t2, SLOPE * t2);
            float t3 = fmaf(acc[3], r2c[mt * 4 + 3], mr2c[mt * 4 + 3]); t3 = fmaxf(t3, SLOPE * t3);
            unsigned long long pk =
                (unsigned long long)((unsigned)f2bf(t0) | ((unsigned)f2bf(t1) << 16)) |
                ((unsigned long long)((unsigned)f2bf(t2) | ((unsigned)f2bf(t3) << 16)) << 32);
            int chunk = mt * 2 + (q >> 1);
            int addr = row * 128 + ((chunk ^ r7) << 4) + (q & 1) * 8;
            *(unsigned long long*)(tile + addr) = pk;
        }
    }
    load_bfrags(W3, l15, q, aw);   // overlaps the barrier wait
    __syncthreads();
    // read a2 frags into regs
#pragma unroll
    for (int nt = 0; nt < 5; ++nt) {
        int row = (w * 5 + nt) * 16 + l15;
        int r7 = row & 7;
        bf[nt][0] = *(const bf16x8*)(tile + row * 128 + ((q ^ r7) << 4));
        bf[nt][1] = *(const bf16x8*)(tile + row * 128 + (((4 + q) ^ r7) << 4));
    }
    __syncthreads();
    // GEMM3 -> pre-norm h3 tile
#pragma unroll
    for (int nt = 0; nt < 5; ++nt) {
        int row = (w * 5 + nt) * 16 + l15;
        int r7 = row & 7;
#pragma unroll
        for (int mt = 0; mt < 4; ++mt) {
            f32x4 acc = (f32x4){0.f, 0.f, 0.f, 0.f};
            acc = __builtin_amdgcn_mfma_f32_16x16x32_bf16(aw[mt][0], bf[nt][0], acc, 0, 0, 0);
            acc = __builtin_amdgcn_mfma_f32_16x16x32_bf16(aw[mt][1], bf[nt][1], acc, 0, 0, 0);
            unsigned long long pk =
                (unsigned long long)((unsigned)f2bf(acc[0]) | ((unsigned)f2bf(acc[1]) << 16)) |
                ((unsigned long long)((unsigned)f2bf(acc[2]) | ((unsigned)f2bf(acc[3]) << 16)) << 32);
            int chunk = mt * 2 + (q >> 1);
            int addr = row * 128 + ((chunk ^ r7) << 4) + (q & 1) * 8;
            *(unsigned long long*)(tile + addr) = pk;
        }
    }
    __syncthreads();
    // max over k=20 + stats3 (b32 reads; thread = (channel-pair, 2 points))
    {
        int c2 = (tid & 31) * 2;
        int pslot = tid >> 5;
        int chunkc = c2 >> 3, inb = (c2 & 7) * 2;
        float ss0 = 0.f, ss1 = 0.f, qs0 = 0.f, qs1 = 0.f;
#pragma unroll
        for (int half = 0; half < 2; ++half) {
            int p = pslot + half * 8;
            float mx0 = -3.4e38f, mx1 = -3.4e38f;
            for (int kk = 0; kk < 20; ++kk) {
                int row = p * 20 + kk;
                unsigned dv = *(const unsigned*)(tile + row * 128 +
                               ((chunkc ^ (row & 7)) << 4) + inb);
                float f0 = bf2f((unsigned short)(dv & 0xFFFF));
                float f1 = bf2f((unsigned short)(dv >> 16));
                mx0 = fmaxf(mx0, f0); mx1 = fmaxf(mx1, f1);
                ss0 += f0; qs0 = fmaf(f0, f0, qs0);
                ss1 += f1; qs1 = fmaf(f1, f1, qs1);
            }
            float2 o2 = make_float2(mx0, mx1);
            *(float2*)(out + (size_t)(base + p) * 64 + c2) = o2;
        }
        red[tid] = ss0; red[256 + tid] = ss1;
        red[512 + tid] = qs0; red[768 + tid] = qs1;
    }
    __syncthreads();
    if (tid < 64) {
        int pi = tid >> 1, par = tid & 1;
        float sa = 0.f, qa = 0.f;
#pragma unroll
        for (int g = 0; g < 8; ++g) {
            sa += red[par * 256 + g * 32 + pi];
            qa += red[512 + par * 256 + g * 32 + pi];
        }
        atomicAdd(&s3[b * 64 + tid], sa);
        atomicAdd(&s3[512 + b * 64 + tid], qa);
    }
}

// ---------------- K4: out = lrelu((out - mean3) * rstd3), in place ----------------
__global__ __launch_bounds__(256) void k4_final(float* __restrict__ out,
        const float* __restrict__ s3) {
    int idx = blockIdx.x * 256 + threadIdx.x;
    int c = idx & 63;
    int b = idx >> 18;
    const float inv = 1.0f / (float)NKCNT;
    float mm = s3[b * 64 + c] * inv;
    float vv = s3[512 + b * 64 + c] * inv - mm * mm;
    float r = rsqrtf(vv + EPSI);
    float val = (out[idx] - mm) * r;
    out[idx] = val >= 0.f ? val : SLOPE * val;
}

extern "C" void kernel_launch(void* const* d_in, const int* in_sizes, int n_in,
                              void* d_out, int out_size, void* d_ws, size_t ws_size,
                              hipStream_t stream) {
    const float* x   = (const float*)d_in[0];
    const int*   ind = (const int*)d_in[1];
    const float* W1  = (const float*)d_in[2];
    const float* W2  = (const float*)d_in[3];
    const float* W3  = (const float*)d_in[4];
    float* out = (float*)d_out;

    unsigned short* u = (unsigned short*)d_ws;            // [32768][64] bf16
    unsigned short* v = u + BN * 64;                      // [32768][64] bf16
    float* stats = (float*)(v + BN * 64);
    float* s1 = stats;          // [2][512]
    float* s2 = stats + 1024;   // [2][512]
    float* s3 = stats + 2048;   // [2][512]

    hipMemsetAsync(stats, 0, 3 * 1024 * sizeof(float), stream);
    k0_uv<<<dim3(BN / 16), dim3(256), 0, stream>>>(x, W1, u, v);
    k1_stats1<<<dim3(BN / 64), dim3(256), 0, stream>>>(u, v, ind, s1);
    k2_stats2<<<dim3(BN / 16), dim3(256), 0, stream>>>(u, v, ind, W2, s1, s2);
    k3_gemm3<<<dim3(BN / 16), dim3(256), 0, stream>>>(u, v, ind, W2, W3, s1, s2, s3, out);
    k4_final<<<dim3(BN * 64 / 256), dim3(256), 0, stream>>>(out, s3);
}

// Round 6
// 217.731 us; speedup vs baseline: 1.2245x; 1.2245x over previous
//
#include <hip/hip_runtime.h>

#define BDIM 8
#define NPTS 4096
#define KNEI 20
#define BN (BDIM*NPTS)        // 32768
#define NKCNT (NPTS*KNEI)     // 81920
#define EPSI 1e-5f
#define SLOPE 0.01f

typedef __attribute__((ext_vector_type(8))) short bf16x8;
typedef __attribute__((ext_vector_type(4))) float f32x4;
typedef __attribute__((ext_vector_type(4))) unsigned int u32x4;

__device__ __forceinline__ unsigned short f2bf(float f) {
    unsigned u = __builtin_bit_cast(unsigned, f);
    u += 0x7FFFu + ((u >> 16) & 1u);
    return (unsigned short)(u >> 16);
}
__device__ __forceinline__ float bf2f(unsigned short h) {
    unsigned u = ((unsigned)h) << 16;
    return __builtin_bit_cast(float, u);
}

// async global->LDS DMA, 16 B/lane; per-lane global address (row gather),
// LDS dest = wave-uniform base + lane*16.
__device__ __forceinline__ void async16(const void* g, void* l) {
    __builtin_amdgcn_global_load_lds(
        (const __attribute__((address_space(1))) unsigned int*)g,
        (__attribute__((address_space(3))) unsigned int*)l, 16, 0, 0);
}

// ---------------- K0: u = x*W1a^T, v = x*(W1b-W1a)^T  (bf16 out) ----------------
__global__ __launch_bounds__(256) void k0_uv(const float* __restrict__ x,
        const float* __restrict__ W1, unsigned short* __restrict__ u,
        unsigned short* __restrict__ v) {
    __shared__ float wlds[64 * 129];
    __shared__ float xs[16 * 64];
    int tid = threadIdx.x;
    int m0 = blockIdx.x * 16;
    for (int i = tid; i < 8192; i += 256)
        wlds[(i >> 7) * 129 + (i & 127)] = W1[i];
    for (int i = tid; i < 1024; i += 256)
        xs[i] = x[m0 * 64 + i];
    __syncthreads();
    int o = tid & 63;
    int r0 = tid >> 6;
    float au[4] = {0.f, 0.f, 0.f, 0.f};
    float av[4] = {0.f, 0.f, 0.f, 0.f};
    for (int c = 0; c < 64; ++c) {
        float wa = wlds[o * 129 + c];
        float wb = wlds[o * 129 + 64 + c];
        float wd = wb - wa;
#pragma unroll
        for (int jj = 0; jj < 4; ++jj) {
            float xv = xs[(r0 + jj * 4) * 64 + c];
            au[jj] += xv * wa;
            av[jj] += xv * wd;
        }
    }
#pragma unroll
    for (int jj = 0; jj < 4; ++jj) {
        int m = m0 + r0 + jj * 4;
        u[m * 64 + o] = f2bf(au[jj]);
        v[m * 64 + o] = f2bf(av[jj]);
    }
}

// ---- helper: load A-fragments (W row-major [64][64] fp32 -> bf16 frags) ----
__device__ __forceinline__ void load_bfrags(const float* __restrict__ W,
        int l15, int q, bf16x8 bw[4][2]) {
#pragma unroll
    for (int mt = 0; mt < 4; ++mt)
#pragma unroll
        for (int kc = 0; kc < 2; ++kc) {
            const float* wp = W + (mt * 16 + l15) * 64 + kc * 32 + q * 8;
            bf16x8 t;
#pragma unroll
            for (int j = 0; j < 8; ++j) t[j] = (short)f2bf(wp[j]);
            bw[mt][kc] = t;
        }
}

// ---- helper: issue the 8-point tile gather DMAs (160 rows u-gather + 8 rows v) ----
__device__ __forceinline__ void dma_gather(const unsigned short* __restrict__ u,
        const unsigned short* __restrict__ v, const int* __restrict__ ind,
        unsigned char* tile, unsigned char* vt, int base, int base20,
        int lane, int w) {
    if (w == 0)
        async16(v + (size_t)(base + (lane >> 3)) * 64 + (lane & 7) * 8, vt);
    int swz = (lane & 7) ^ ((lane >> 3) & 7);
    int idxr[10];
#pragma unroll
    for (int j = 0; j < 10; ++j)
        idxr[j] = ind[base20 + (w * 10 + j) * 8 + (lane >> 3)];
#pragma unroll
    for (int j = 0; j < 10; ++j)
        async16(u + (size_t)idxr[j] * 64 + swz * 8, tile + (w * 10 + j) * 1024);
}

// ---------------- K1: stats1 of h1 = u[ind]+v (8-pt tile, 2-wave block) ----------------
__global__ __launch_bounds__(128) void k1_stats1(const unsigned short* __restrict__ u,
        const unsigned short* __restrict__ v, const int* __restrict__ ind,
        float* __restrict__ s1p) {
    __shared__ __align__(16) unsigned char tile[20480];   // 160 rows x 128 B, swizzled
    __shared__ __align__(16) unsigned char vt[1024];      // 8 rows x 128 B, identity
    __shared__ float red[256];
    int tid = threadIdx.x;
    int lane = tid & 63, w = tid >> 6;
    int blk = blockIdx.x;
    int b = blk >> 9;                    // 512 blocks per batch
    int n0 = (blk & 511) << 3;           // 8 points
    int base = b * NPTS + n0;
    int base20 = base * 20;
    dma_gather(u, v, ind, tile, vt, base, base20, lane, w);
    __syncthreads();
    int c2 = (tid & 31) * 2;
    int rr = tid >> 5;                   // 0..3
    float sA = 0.f, qA = 0.f, sB = 0.f, qB = 0.f;
    for (int j = 0; j < 40; ++j) {
        int r = rr + 4 * j;
        int p = (r * 3277) >> 16;        // r/20
        unsigned uu = *(const unsigned*)(tile + r * 128 +
                        (((c2 >> 3) ^ (r & 7)) << 4) + ((c2 & 7) * 2));
        unsigned vv = *(const unsigned*)(vt + p * 128 + c2 * 2);
        float h0 = bf2f((unsigned short)(uu & 0xFFFF)) + bf2f((unsigned short)(vv & 0xFFFF));
        float h1 = bf2f((unsigned short)(uu >> 16)) + bf2f((unsigned short)(vv >> 16));
        sA += h0; qA = fmaf(h0, h0, qA);
        sB += h1; qB = fmaf(h1, h1, qB);
    }
    sA += __shfl_xor(sA, 32, 64); qA += __shfl_xor(qA, 32, 64);
    sB += __shfl_xor(sB, 32, 64); qB += __shfl_xor(qB, 32, 64);
    if (lane < 32) {
        red[w * 128 + lane * 4 + 0] = sA;
        red[w * 128 + lane * 4 + 1] = qA;
        red[w * 128 + lane * 4 + 2] = sB;
        red[w * 128 + lane * 4 + 3] = qB;
    }
    __syncthreads();
    {
        int c = tid & 63, st = tid >> 6;
        int o = (c >> 1) * 4 + (c & 1) * 2 + st;
        float a = red[o] + red[128 + o];
        atomicAdd(&s1p[(blk & 7) * 1024 + st * 512 + b * 64 + c], a);
    }
}

// ---------------- kred: s[i] = sum over 8 partials ----------------
__global__ __launch_bounds__(256) void kred(const float* __restrict__ p,
        float* __restrict__ s) {
    int i = blockIdx.x * 256 + threadIdx.x;   // < 1024
    float a = 0.f;
#pragma unroll
    for (int g = 0; g < 8; ++g) a += p[g * 1024 + i];
    s[i] = a;
}

// ------ K2: gather -> norm1+lrelu -> GEMM2 -> register stats2 (8-pt, 2-wave) ------
__global__ __launch_bounds__(128) void k2_stats2(const unsigned short* __restrict__ u,
        const unsigned short* __restrict__ v, const int* __restrict__ ind,
        const float* __restrict__ W2, const float* __restrict__ s1,
        float* __restrict__ s2p) {
    __shared__ __align__(16) unsigned char tile[20480];
    __shared__ __align__(16) unsigned char vt[1024];
    __shared__ float red[256];
    int tid = threadIdx.x;
    int lane = tid & 63, w = tid >> 6;
    int l15 = lane & 15, q = lane >> 4;
    int blk = blockIdx.x;
    int b = blk >> 9;
    int n0 = (blk & 511) << 3;
    int base = b * NPTS + n0;
    int base20 = base * 20;
    bf16x8 aw[4][2];
    load_bfrags(W2, l15, q, aw);
    const float inv = 1.0f / (float)NKCNT;
    float r1[2][8], mr1[2][8];
#pragma unroll
    for (int kc = 0; kc < 2; ++kc)
#pragma unroll
        for (int j = 0; j < 8; ++j) {
            int c = kc * 32 + q * 8 + j;
            float mm = s1[b * 64 + c] * inv;
            float vv = s1[512 + b * 64 + c] * inv - mm * mm;
            float rs = rsqrtf(vv + EPSI);
            r1[kc][j] = rs; mr1[kc][j] = -mm * rs;
        }
    dma_gather(u, v, ind, tile, vt, base, base20, lane, w);
    __syncthreads();
    bf16x8 bf[5][2];
#pragma unroll
    for (int nt = 0; nt < 5; ++nt) {
        int row = (w * 5 + nt) * 16 + l15;
        int p = (row * 3277) >> 16;
#pragma unroll
        for (int kc = 0; kc < 2; ++kc) {
            int phys = (((kc * 4 + q) ^ (row & 7)) << 4);
            bf16x8 ub = *(const bf16x8*)(tile + row * 128 + phys);
            bf16x8 vb = *(const bf16x8*)(vt + p * 128 + kc * 64 + q * 16);
            bf16x8 o;
#pragma unroll
            for (int j = 0; j < 8; ++j) {
                float hval = bf2f((unsigned short)ub[j]) + bf2f((unsigned short)vb[j]);
                float t = fmaf(hval, r1[kc][j], mr1[kc][j]);
                t = fmaxf(t, SLOPE * t);
                o[j] = (short)f2bf(t);
            }
            bf[nt][kc] = o;
        }
    }
#pragma unroll
    for (int mt = 0; mt < 4; ++mt) {
        float s4[4] = {0.f, 0.f, 0.f, 0.f}, q4[4] = {0.f, 0.f, 0.f, 0.f};
#pragma unroll
        for (int nt = 0; nt < 5; ++nt) {
            f32x4 acc = (f32x4){0.f, 0.f, 0.f, 0.f};
            acc = __builtin_amdgcn_mfma_f32_16x16x32_bf16(aw[mt][0], bf[nt][0], acc, 0, 0, 0);
            acc = __builtin_amdgcn_mfma_f32_16x16x32_bf16(aw[mt][1], bf[nt][1], acc, 0, 0, 0);
#pragma unroll
            for (int i = 0; i < 4; ++i) {
                s4[i] += acc[i];
                q4[i] = fmaf(acc[i], acc[i], q4[i]);
            }
        }
#pragma unroll
        for (int m = 1; m <= 8; m <<= 1)
#pragma unroll
            for (int i = 0; i < 4; ++i) {
                s4[i] += __shfl_xor(s4[i], m, 64);
                q4[i] += __shfl_xor(q4[i], m, 64);
            }
        if (l15 == 0) {
#pragma unroll
            for (int i = 0; i < 4; ++i) {
                int c = mt * 16 + q * 4 + i;
                red[w * 128 + c] = s4[i];
                red[w * 128 + 64 + c] = q4[i];
            }
        }
    }
    __syncthreads();
    {
        int c = tid & 63, st = tid >> 6;
        float a = red[st * 64 + c] + red[128 + st * 64 + c];
        atomicAdd(&s2p[(blk & 7) * 1024 + st * 512 + b * 64 + c], a);
    }
}

// -- K3: gather -> a1 -> GEMM2 -> norm2(write-side) -> a2 -> GEMM3 -> max/stats3 -> out --
__global__ __launch_bounds__(128) void k3_gemm3(const unsigned short* __restrict__ u,
        const unsigned short* __restrict__ v, const int* __restrict__ ind,
        const float* __restrict__ W2, const float* __restrict__ W3,
        const float* __restrict__ s1, const float* __restrict__ s2,
        float* __restrict__ s3p, float* __restrict__ out) {
    __shared__ __align__(16) unsigned char tile[20480];
    __shared__ __align__(16) unsigned char vt[1024];
    __shared__ float red[512];
    int tid = threadIdx.x;
    int lane = tid & 63, w = tid >> 6;
    int l15 = lane & 15, q = lane >> 4;
    int blk = blockIdx.x;
    int b = blk >> 9;
    int n0 = (blk & 511) << 3;
    int base = b * NPTS + n0;
    int base20 = base * 20;
    bf16x8 aw[4][2];
    load_bfrags(W2, l15, q, aw);
    const float inv = 1.0f / (float)NKCNT;
    float r1[2][8], mr1[2][8];
#pragma unroll
    for (int kc = 0; kc < 2; ++kc)
#pragma unroll
        for (int j = 0; j < 8; ++j) {
            int c = kc * 32 + q * 8 + j;
            float mm = s1[b * 64 + c] * inv;
            float vv = s1[512 + b * 64 + c] * inv - mm * mm;
            float rs = rsqrtf(vv + EPSI);
            r1[kc][j] = rs; mr1[kc][j] = -mm * rs;
        }
    float r2c[16], mr2c[16];
#pragma unroll
    for (int e = 0; e < 16; ++e) {
        int c = (e >> 2) * 16 + q * 4 + (e & 3);
        float mm = s2[b * 64 + c] * inv;
        float vv = s2[512 + b * 64 + c] * inv - mm * mm;
        float rs = rsqrtf(vv + EPSI);
        r2c[e] = rs; mr2c[e] = -mm * rs;
    }
    dma_gather(u, v, ind, tile, vt, base, base20, lane, w);
    __syncthreads();
    // a1 fragments (wave w touches only rows [w*80, w*80+80))
    bf16x8 bf[5][2];
#pragma unroll
    for (int nt = 0; nt < 5; ++nt) {
        int row = (w * 5 + nt) * 16 + l15;
        int p = (row * 3277) >> 16;
#pragma unroll
        for (int kc = 0; kc < 2; ++kc) {
            int phys = (((kc * 4 + q) ^ (row & 7)) << 4);
            bf16x8 ub = *(const bf16x8*)(tile + row * 128 + phys);
            bf16x8 vb = *(const bf16x8*)(vt + p * 128 + kc * 64 + q * 16);
            bf16x8 o;
#pragma unroll
            for (int j = 0; j < 8; ++j) {
                float hval = bf2f((unsigned short)ub[j]) + bf2f((unsigned short)vb[j]);
                float t = fmaf(hval, r1[kc][j], mr1[kc][j]);
                t = fmaxf(t, SLOPE * t);
                o[j] = (short)f2bf(t);
            }
            bf[nt][kc] = o;
        }
    }
    // GEMM2 + write-side norm2+lrelu -> a2 into own rows (per-wave in-order LDS)
#pragma unroll
    for (int nt = 0; nt < 5; ++nt) {
        int row = (w * 5 + nt) * 16 + l15;
        int r7 = row & 7;
#pragma unroll
        for (int mt = 0; mt < 4; ++mt) {
            f32x4 acc = (f32x4){0.f, 0.f, 0.f, 0.f};
            acc = __builtin_amdgcn_mfma_f32_16x16x32_bf16(aw[mt][0], bf[nt][0], acc, 0, 0, 0);
            acc = __builtin_amdgcn_mfma_f32_16x16x32_bf16(aw[mt][1], bf[nt][1], acc, 0, 0, 0);
            float t0 = fmaf(acc[0], r2c[mt * 4 + 0], mr2c[mt * 4 + 0]); t0 = fmaxf(t0, SLOPE * t0);
            float t1 = fmaf(acc[1], r2c[mt * 4 + 1], mr2c[mt * 4 + 1]); t1 = fmaxf(t1, SLOPE * t1);
            float t2 = fmaf(acc[2], r2c[mt * 4 + 2], mr2c[mt * 4 + 2]); t2 = fmaxf(t2, SLOPE * t2);
            float t3 = fmaf(acc[3], r2c[mt * 4 + 3], mr2c[mt * 4 + 3]); t3 = fmaxf(t3, SLOPE * t3);
            unsigned long long pk =
                (unsigned long long)((unsigned)f2bf(t0) | ((unsigned)f2bf(t1) << 16)) |
                ((unsigned long long)((unsigned)f2bf(t2) | ((unsigned)f2bf(t3) << 16)) << 32);
            int chunk = mt * 2 + (q >> 1);
            int addr = row * 128 + ((chunk ^ r7) << 4) + (q & 1) * 8;
            *(unsigned long long*)(tile + addr) = pk;
        }
    }
    load_bfrags(W3, l15, q, aw);
    // GEMM3: read a2 frags (own rows), write pre-norm h3 back (own rows)
#pragma unroll
    for (int nt = 0; nt < 5; ++nt) {
        int row = (w * 5 + nt) * 16 + l15;
        int r7 = row & 7;
        bf16x8 b0 = *(const bf16x8*)(tile + row * 128 + ((q ^ r7) << 4));
        bf16x8 b1 = *(const bf16x8*)(tile + row * 128 + (((4 + q) ^ r7) << 4));
#pragma unroll
        for (int mt = 0; mt < 4; ++mt) {
            f32x4 acc = (f32x4){0.f, 0.f, 0.f, 0.f};
            acc = __builtin_amdgcn_mfma_f32_16x16x32_bf16(aw[mt][0], b0, acc, 0, 0, 0);
            acc = __builtin_amdgcn_mfma_f32_16x16x32_bf16(aw[mt][1], b1, acc, 0, 0, 0);
            unsigned long long pk =
                (unsigned long long)((unsigned)f2bf(acc[0]) | ((unsigned)f2bf(acc[1]) << 16)) |
                ((unsigned long long)((unsigned)f2bf(acc[2]) | ((unsigned)f2bf(acc[3]) << 16)) << 32);
            int chunk = mt * 2 + (q >> 1);
            int addr = row * 128 + ((chunk ^ r7) << 4) + (q & 1) * 8;
            *(unsigned long long*)(tile + addr) = pk;
        }
    }
    __syncthreads();   // cross-wave: max phase reads all 160 rows
    {
        int c2 = (tid & 31) * 2;
        int pg = tid >> 5;               // 0..3
        int chunkc = c2 >> 3, inb = (c2 & 7) * 2;
        float ss0 = 0.f, ss1 = 0.f, qs0 = 0.f, qs1 = 0.f;
#pragma unroll
        for (int half = 0; half < 2; ++half) {
            int p = pg + half * 4;
            float mx0 = -3.4e38f, mx1 = -3.4e38f;
            for (int kk = 0; kk < 20; ++kk) {
                int row = p * 20 + kk;
                unsigned dv = *(const unsigned*)(tile + row * 128 +
                               ((chunkc ^ (row & 7)) << 4) + inb);
                float f0 = bf2f((unsigned short)(dv & 0xFFFF));
                float f1 = bf2f((unsigned short)(dv >> 16));
                mx0 = fmaxf(mx0, f0); mx1 = fmaxf(mx1, f1);
                ss0 += f0; qs0 = fmaf(f0, f0, qs0);
                ss1 += f1; qs1 = fmaf(f1, f1, qs1);
            }
            *(float2*)(out + (size_t)(base + p) * 64 + c2) = make_float2(mx0, mx1);
        }
        red[tid * 4 + 0] = ss0; red[tid * 4 + 1] = qs0;
        red[tid * 4 + 2] = ss1; red[tid * 4 + 3] = qs1;
    }
    __syncthreads();
    {
        int c = tid & 63, st = tid >> 6;
        float a = 0.f;
#pragma unroll
        for (int pg = 0; pg < 4; ++pg)
            a += red[(pg * 32 + (c >> 1)) * 4 + (c & 1) * 2 + st];
        atomicAdd(&s3p[(blk & 7) * 1024 + st * 512 + b * 64 + c], a);
    }
}

// ---------------- K4: out = lrelu((out - mean3) * rstd3), in place ----------------
__global__ __launch_bounds__(256) void k4_final(float* __restrict__ out,
        const float* __restrict__ s3) {
    int idx = blockIdx.x * 256 + threadIdx.x;
    int c = idx & 63;
    int b = idx >> 18;
    const float inv = 1.0f / (float)NKCNT;
    float mm = s3[b * 64 + c] * inv;
    float vv = s3[512 + b * 64 + c] * inv - mm * mm;
    float r = rsqrtf(vv + EPSI);
    float val = (out[idx] - mm) * r;
    out[idx] = val >= 0.f ? val : SLOPE * val;
}

extern "C" void kernel_launch(void* const* d_in, const int* in_sizes, int n_in,
                              void* d_out, int out_size, void* d_ws, size_t ws_size,
                              hipStream_t stream) {
    const float* x   = (const float*)d_in[0];
    const int*   ind = (const int*)d_in[1];
    const float* W1  = (const float*)d_in[2];
    const float* W2  = (const float*)d_in[3];
    const float* W3  = (const float*)d_in[4];
    float* out = (float*)d_out;

    unsigned short* u = (unsigned short*)d_ws;            // [32768][64] bf16
    unsigned short* v = u + BN * 64;                      // [32768][64] bf16
    float* sp  = (float*)(v + BN * 64);
    float* s1p = sp;               // [8][2][512] partials
    float* s2p = sp + 8192;
    float* s3p = sp + 16384;
    float* s1  = sp + 24576;       // [2][512] reduced
    float* s2  = sp + 25600;
    float* s3  = sp + 26624;

    hipMemsetAsync(sp, 0, 3 * 8192 * sizeof(float), stream);
    k0_uv<<<dim3(BN / 16), dim3(256), 0, stream>>>(x, W1, u, v);
    k1_stats1<<<dim3(BN / 8), dim3(128), 0, stream>>>(u, v, ind, s1p);
    kred<<<dim3(4), dim3(256), 0, stream>>>(s1p, s1);
    k2_stats2<<<dim3(BN / 8), dim3(128), 0, stream>>>(u, v, ind, W2, s1, s2p);
    kred<<<dim3(4), dim3(256), 0, stream>>>(s2p, s2);
    k3_gemm3<<<dim3(BN / 8), dim3(128), 0, stream>>>(u, v, ind, W2, W3, s1, s2, s3p, out);
    kred<<<dim3(4), dim3(256), 0, stream>>>(s3p, s3);
    k4_final<<<dim3(BN * 64 / 256), dim3(256), 0, stream>>>(out, s3);
}